// Round 4
// baseline (3802.007 us; speedup 1.0000x reference)
//
#include <hip/hip_runtime.h>

// ---------------------------------------------------------------------------
// BidirRecurrentModel: 2-layer bidirectional GRU (both layers read raw x).
// Phase 1: gx = x@Wx^T + bx   (f16 MFMA GEMM, gx fp16 in workspace)
// Phase 2: 128 chains (b,l,dir), sequential T=2048.
//   R4: 1024 threads/block, thread (i,q): unit i in [0,256), k-quarter q in
//   [0,4) owning 64 cols. Weights = 96 fp16x2 VGPRs (fits the 128-reg cap the
//   allocator enforces regardless of launch_bounds/waves_per_eu — measured
//   R0-R3). Cross-q reduce via __shfl_xor(16|32). One barrier/step.
// ---------------------------------------------------------------------------

typedef _Float16 half8 __attribute__((ext_vector_type(8)));
typedef _Float16 half2_t __attribute__((ext_vector_type(2)));
typedef float floatx4 __attribute__((ext_vector_type(4)));

__device__ __forceinline__ float sigmoidf_fast(float x) {
    return 1.0f / (1.0f + __expf(-x));
}

__device__ __forceinline__ float tanh_fast(float x) {
    float ax = fabsf(x);
    float e = __expf(-2.0f * ax);
    float t = (1.0f - e) / (1.0f + e);
    return copysignf(t, x);
}

// ---------------------------------------------------------------------------
// Kernel 1: gx GEMM.  C[M=65536][N=1536] = x[M][256] * Wx[N][256]^T + bx[N]
// (unchanged — not the bottleneck)
// ---------------------------------------------------------------------------
__global__ __launch_bounds__(256) void gemm_gx_kernel(
    const float* __restrict__ x,
    const float* __restrict__ Wx,
    const float* __restrict__ bx,
    _Float16* __restrict__ gx)
{
    __shared__ __align__(16) char lds[32768];
    _Float16* As = (_Float16*)lds;            // [4][128][8] fp16 (8 KB)
    _Float16* Bs = (_Float16*)(lds + 8192);   // [4][128][8] fp16 (8 KB)

    const int tid = threadIdx.x;
    const int m0 = blockIdx.x * 128;
    const int n0 = blockIdx.y * 128;
    const int wave = tid >> 6;
    const int lane = tid & 63;
    const int wm = wave & 1;
    const int wn = wave >> 1;
    const int frag = lane & 15;
    const int kg = lane >> 4;

    floatx4 acc[4][4];
#pragma unroll
    for (int a = 0; a < 4; ++a)
#pragma unroll
        for (int b = 0; b < 4; ++b)
            acc[a][b] = (floatx4){0.f, 0.f, 0.f, 0.f};

    for (int k0 = 0; k0 < 256; k0 += 32) {
        __syncthreads();
#pragma unroll
        for (int rep = 0; rep < 2; ++rep) {
            int idx = tid + rep * 256;   // 512 slots of 8 elems = 128x32 tile
            int row = idx >> 2;
            int kc = idx & 3;
            const float4* ap = (const float4*)(x + (size_t)(m0 + row) * 256 + k0 + kc * 8);
            const float4* bp = (const float4*)(Wx + (size_t)(n0 + row) * 256 + k0 + kc * 8);
            float4 a0 = ap[0], a1 = ap[1];
            float4 b0 = bp[0], b1 = bp[1];
            half8 av = {(_Float16)a0.x, (_Float16)a0.y, (_Float16)a0.z, (_Float16)a0.w,
                        (_Float16)a1.x, (_Float16)a1.y, (_Float16)a1.z, (_Float16)a1.w};
            half8 bv = {(_Float16)b0.x, (_Float16)b0.y, (_Float16)b0.z, (_Float16)b0.w,
                        (_Float16)b1.x, (_Float16)b1.y, (_Float16)b1.z, (_Float16)b1.w};
            *(half8*)(As + (kc * 128 + row) * 8) = av;
            *(half8*)(Bs + (kc * 128 + row) * 8) = bv;
        }
        __syncthreads();

        half8 af[4], bfr[4];
#pragma unroll
        for (int tm = 0; tm < 4; ++tm)
            af[tm] = *(const half8*)(As + (kg * 128 + wm * 64 + tm * 16 + frag) * 8);
#pragma unroll
        for (int tn = 0; tn < 4; ++tn)
            bfr[tn] = *(const half8*)(Bs + (kg * 128 + wn * 64 + tn * 16 + frag) * 8);
#pragma unroll
        for (int tm = 0; tm < 4; ++tm)
#pragma unroll
            for (int tn = 0; tn < 4; ++tn)
                acc[tm][tn] = __builtin_amdgcn_mfma_f32_16x16x32_f16(
                    af[tm], bfr[tn], acc[tm][tn], 0, 0, 0);
    }

    __syncthreads();
    // Epilogue: bias add, fp16 convert, re-layout via LDS for coalesced stores.
    _Float16* epi = (_Float16*)lds;  // [128][128]
#pragma unroll
    for (int tm = 0; tm < 4; ++tm) {
#pragma unroll
        for (int tn = 0; tn < 4; ++tn) {
            int col = wn * 64 + tn * 16 + frag;
            float bias = bx[n0 + col];
#pragma unroll
            for (int r = 0; r < 4; ++r) {
                int rowc = wm * 64 + tm * 16 + kg * 4 + r;  // C/D: col=lane&15, row=quad*4+reg
                epi[rowc * 128 + col] = (_Float16)(acc[tm][tn][r] + bias);
            }
        }
    }
    __syncthreads();

    // copy out: each thread -> 64 contiguous fp16 of one row
    int row = tid >> 1;
    int hs = tid & 1;
    int gm = m0 + row;
    int bb = gm >> 11;          // batch
    int tt = gm & 2047;         // time
    int l = n0 / 768;           // 768 % 128 == 0, so a block never crosses l
    int g0 = n0 - l * 768 + hs * 64;
    size_t oidx = (((size_t)bb * 2 + l) * 2048 + tt) * 768 + g0;
    const uint4* s = (const uint4*)(epi + row * 128 + hs * 64);
    uint4* d = (uint4*)(gx + oidx);
#pragma unroll
    for (int j = 0; j < 8; ++j) d[j] = s[j];
}

// ---------------------------------------------------------------------------
// Kernel 2: the recurrence. One block per chain (b, l, dir); 128 blocks.
// 1024 threads = 16 waves. wave w handles units [w*16, w*16+16).
// Lane layout: i = w*16 + (lane&15), q = lane>>4 (k-quarter).
// Thread owns Wh rows {i, 256+i, 512+i}, cols [q*64, q*64+64) as 96 fp16x2
// VGPRs, loaded in per-q rotated chunk order so the per-step ds_read_b128 of
// h hits 16 distinct banks across the 4 q-groups (unrotated: all 4 groups'
// addresses are 128B apart -> same banks 0-3 -> 4-way conflict).
// h fp16 double-buffered in LDS; gx prefetched one step ahead to registers.
// Per step: 96 v_dot2 x3-gate interleaved, 2x shfl_xor reduce, gate math
// (redundant across q — same issue cost as exec-masked), one barrier.
// ---------------------------------------------------------------------------
__global__ __launch_bounds__(1024) void gru_scan_kernel(
    const float* __restrict__ Wh,
    const float* __restrict__ bh,
    const _Float16* __restrict__ gx,
    float* __restrict__ out)
{
    const int c = blockIdx.x;
    const int b = c & 31;
    const int l = (c >> 5) & 1;
    const int dir = c >> 6;
    const int tid = threadIdx.x;
    const int wave = tid >> 6;
    const int lane = tid & 63;
    const int q = lane >> 4;                 // k-quarter: cols [q*64, q*64+64)
    const int i = wave * 16 + (lane & 15);   // output unit 0..255

    __shared__ __align__(16) _Float16 h2[2][256];  // double-buffered fp16 h

    // --- load Wh into registers, fp32 -> fp16x2, rotated chunk order ---
    // slot j (j=0..7, 4 half2 each) holds global chunk g=(j+2q)&7 of this
    // thread's 64-col slice; dot phase reads h chunk g at the same slot.
    half2_t wr[32], wz[32], wn_[32];
    {
        const float2* pr = (const float2*)(Wh + ((size_t)l * 768 + i) * 256 + q * 64);
        const float2* pz = (const float2*)(Wh + ((size_t)l * 768 + 256 + i) * 256 + q * 64);
        const float2* pn = (const float2*)(Wh + ((size_t)l * 768 + 512 + i) * 256 + q * 64);
#pragma unroll
        for (int j = 0; j < 8; ++j) {
            int g = (j + 2 * q) & 7;
#pragma unroll
            for (int d = 0; d < 4; ++d) {
                float2 a = pr[4 * g + d];
                float2 bb2 = pz[4 * g + d];
                float2 cc = pn[4 * g + d];
                wr[4 * j + d]  = (half2_t){(_Float16)a.x, (_Float16)a.y};
                wz[4 * j + d]  = (half2_t){(_Float16)bb2.x, (_Float16)bb2.y};
                wn_[4 * j + d] = (half2_t){(_Float16)cc.x, (_Float16)cc.y};
            }
        }
    }

    const float bhr = bh[l * 768 + i];
    const float bhz = bh[l * 768 + 256 + i];
    const float bhn = bh[l * 768 + 512 + i];

    const _Float16* gxp = gx + (size_t)(b * 2 + l) * 2048 * 768;
    // out flat index: ((b*4096) + t*2 + l)*512 + dir*256 + i
    float* outp = out + (size_t)b * 2048 * 1024 + (size_t)l * 512 + dir * 256 + i;

    if (tid < 256) h2[0][tid] = (_Float16)0.f;

    // preload gx for the first step (all lanes of a unit load same addr; dups
    // coalesce into one L2 request)
    const int t0 = dir ? 2047 : 0;
    float cxr = (float)gxp[(size_t)t0 * 768 + i];
    float cxz = (float)gxp[(size_t)t0 * 768 + 256 + i];
    float cxn = (float)gxp[(size_t)t0 * 768 + 512 + i];
    __syncthreads();

    float hreg = 0.f;

    for (int s = 0; s < 2048; ++s) {
        const int t = dir ? (2047 - s) : s;
        const int sn = (s < 2047) ? (s + 1) : s;
        const int tn = dir ? (2047 - sn) : sn;

        // prefetch next step's gx (hidden behind the dot phase)
        float pxr = (float)gxp[(size_t)tn * 768 + i];
        float pxz = (float)gxp[(size_t)tn * 768 + 256 + i];
        float pxn = (float)gxp[(size_t)tn * 768 + 512 + i];

        // --- dot phase: 3 gates x 32 half2 = 96 v_dot2; h via 8 b128 reads ---
        float ar = 0.f, az = 0.f, an = 0.f;
        const char* hb = (const char*)(&h2[s & 1][0]);
#pragma unroll
        for (int j = 0; j < 8; ++j) {
            // rotated chunk: byte offset q*128 + ((j+2q)&7)*16, always inside
            // this thread's own 128B q-region
            uint4 hv = *(const uint4*)(hb + q * 128 + (((j + 2 * q) & 7) << 4));
            half2_t h0 = __builtin_bit_cast(half2_t, hv.x);
            half2_t h1 = __builtin_bit_cast(half2_t, hv.y);
            half2_t hg = __builtin_bit_cast(half2_t, hv.z);
            half2_t h3 = __builtin_bit_cast(half2_t, hv.w);
            ar = __builtin_amdgcn_fdot2(wr[4 * j + 0], h0, ar, false);
            az = __builtin_amdgcn_fdot2(wz[4 * j + 0], h0, az, false);
            an = __builtin_amdgcn_fdot2(wn_[4 * j + 0], h0, an, false);
            ar = __builtin_amdgcn_fdot2(wr[4 * j + 1], h1, ar, false);
            az = __builtin_amdgcn_fdot2(wz[4 * j + 1], h1, az, false);
            an = __builtin_amdgcn_fdot2(wn_[4 * j + 1], h1, an, false);
            ar = __builtin_amdgcn_fdot2(wr[4 * j + 2], hg, ar, false);
            az = __builtin_amdgcn_fdot2(wz[4 * j + 2], hg, az, false);
            an = __builtin_amdgcn_fdot2(wn_[4 * j + 2], hg, an, false);
            ar = __builtin_amdgcn_fdot2(wr[4 * j + 3], h3, ar, false);
            az = __builtin_amdgcn_fdot2(wz[4 * j + 3], h3, az, false);
            an = __builtin_amdgcn_fdot2(wn_[4 * j + 3], h3, an, false);
        }

        // reduce across the 4 k-quarters (lanes ^16, ^32); all lanes end with
        // the full sums
        ar += __shfl_xor(ar, 16, 64);
        ar += __shfl_xor(ar, 32, 64);
        az += __shfl_xor(az, 16, 64);
        az += __shfl_xor(az, 32, 64);
        an += __shfl_xor(an, 16, 64);
        an += __shfl_xor(an, 32, 64);

        // --- gate math (all lanes, redundant across q; identical values) ---
        float r = sigmoidf_fast(cxr + ar + bhr);
        float z = sigmoidf_fast(cxz + az + bhz);
        float n = tanh_fast(cxn + r * (an + bhn));
        float hnew = (1.f - z) * n + z * hreg;
        hreg = hnew;

        if (q == 0) {
            outp[(size_t)t * 1024] = hnew;
            h2[(s + 1) & 1][i] = (_Float16)hnew;
        }
        cxr = pxr; cxz = pxz; cxn = pxn;
        __syncthreads();
    }
}

// ---------------------------------------------------------------------------
extern "C" void kernel_launch(void* const* d_in, const int* in_sizes, int n_in,
                              void* d_out, int out_size, void* d_ws, size_t ws_size,
                              hipStream_t stream) {
    const float* x  = (const float*)d_in[0];  // (32,2048,256) fp32
    const float* Wx = (const float*)d_in[1];  // (2,768,256)  fp32
    const float* Wh = (const float*)d_in[2];  // (2,768,256)  fp32
    const float* bx = (const float*)d_in[3];  // (2,768)      fp32
    const float* bh = (const float*)d_in[4];  // (2,768)      fp32
    float* out = (float*)d_out;               // (32,4096,512) fp32
    _Float16* gxbuf = (_Float16*)d_ws;        // 100,663,296 fp16 = 201.3 MB

    // Phase 1: gx = x @ Wx^T + bx  (layout [b][l][t][768], fp16)
    gemm_gx_kernel<<<dim3(512, 12), 256, 0, stream>>>(x, Wx, bx, gxbuf);

    // Phase 2: 128 independent (b, l, dir) GRU chains
    gru_scan_kernel<<<dim3(128), 1024, 0, stream>>>(Wh, bh, gxbuf, out);
}

// Round 5
// 2896.445 us; speedup vs baseline: 1.3126x; 1.3126x over previous
//
#include <hip/hip_runtime.h>

// ---------------------------------------------------------------------------
// BidirRecurrentModel: 2-layer bidirectional GRU (both layers read raw x).
// Phase 1: gx = x@Wx^T + bx   (f16 MFMA GEMM, gx fp16 in workspace)
// Phase 2: 128 chains (b,l,dir), sequential T=2048. dot2-based matvec with
//          register-resident Wh (fp16x2).
//
// R5 theory: across R0-R4 the allocator always granted exactly HALF the
// permitted VGPR budget as arch regs (512thr->128, 1024thr->64): the gfx950
// unified-file 50/50 arch/AGPR split that engages when AGPRs are needed.
// AGPRs were needed only because the fully-unrolled weight-init loop peaks
// >256 live regs (192 float2 loads hoisted). Steady state needs only ~227.
// Fix: fence the init loop into small chunks (sched_barrier(0)) so peak
// stays <256 -> no AGPR engagement -> ~227 arch regs -> no per-step
// v_accvgpr_read shuttles (the measured 2.3x VALU inflation).
// ---------------------------------------------------------------------------

typedef _Float16 half8 __attribute__((ext_vector_type(8)));
typedef _Float16 half2_t __attribute__((ext_vector_type(2)));
typedef float floatx4 __attribute__((ext_vector_type(4)));

__device__ __forceinline__ float sigmoidf_fast(float x) {
    return 1.0f / (1.0f + __expf(-x));
}

__device__ __forceinline__ float tanh_fast(float x) {
    float ax = fabsf(x);
    float e = __expf(-2.0f * ax);
    float t = (1.0f - e) / (1.0f + e);
    return copysignf(t, x);
}

// ---------------------------------------------------------------------------
// Kernel 1: gx GEMM.  C[M=65536][N=1536] = x[M][256] * Wx[N][256]^T + bx[N]
// (unchanged — not the bottleneck)
// ---------------------------------------------------------------------------
__global__ __launch_bounds__(256) void gemm_gx_kernel(
    const float* __restrict__ x,
    const float* __restrict__ Wx,
    const float* __restrict__ bx,
    _Float16* __restrict__ gx)
{
    __shared__ __align__(16) char lds[32768];
    _Float16* As = (_Float16*)lds;            // [4][128][8] fp16 (8 KB)
    _Float16* Bs = (_Float16*)(lds + 8192);   // [4][128][8] fp16 (8 KB)

    const int tid = threadIdx.x;
    const int m0 = blockIdx.x * 128;
    const int n0 = blockIdx.y * 128;
    const int wave = tid >> 6;
    const int lane = tid & 63;
    const int wm = wave & 1;
    const int wn = wave >> 1;
    const int frag = lane & 15;
    const int kg = lane >> 4;

    floatx4 acc[4][4];
#pragma unroll
    for (int a = 0; a < 4; ++a)
#pragma unroll
        for (int b = 0; b < 4; ++b)
            acc[a][b] = (floatx4){0.f, 0.f, 0.f, 0.f};

    for (int k0 = 0; k0 < 256; k0 += 32) {
        __syncthreads();
#pragma unroll
        for (int rep = 0; rep < 2; ++rep) {
            int idx = tid + rep * 256;   // 512 slots of 8 elems = 128x32 tile
            int row = idx >> 2;
            int kc = idx & 3;
            const float4* ap = (const float4*)(x + (size_t)(m0 + row) * 256 + k0 + kc * 8);
            const float4* bp = (const float4*)(Wx + (size_t)(n0 + row) * 256 + k0 + kc * 8);
            float4 a0 = ap[0], a1 = ap[1];
            float4 b0 = bp[0], b1 = bp[1];
            half8 av = {(_Float16)a0.x, (_Float16)a0.y, (_Float16)a0.z, (_Float16)a0.w,
                        (_Float16)a1.x, (_Float16)a1.y, (_Float16)a1.z, (_Float16)a1.w};
            half8 bv = {(_Float16)b0.x, (_Float16)b0.y, (_Float16)b0.z, (_Float16)b0.w,
                        (_Float16)b1.x, (_Float16)b1.y, (_Float16)b1.z, (_Float16)b1.w};
            *(half8*)(As + (kc * 128 + row) * 8) = av;
            *(half8*)(Bs + (kc * 128 + row) * 8) = bv;
        }
        __syncthreads();

        half8 af[4], bfr[4];
#pragma unroll
        for (int tm = 0; tm < 4; ++tm)
            af[tm] = *(const half8*)(As + (kg * 128 + wm * 64 + tm * 16 + frag) * 8);
#pragma unroll
        for (int tn = 0; tn < 4; ++tn)
            bfr[tn] = *(const half8*)(Bs + (kg * 128 + wn * 64 + tn * 16 + frag) * 8);
#pragma unroll
        for (int tm = 0; tm < 4; ++tm)
#pragma unroll
            for (int tn = 0; tn < 4; ++tn)
                acc[tm][tn] = __builtin_amdgcn_mfma_f32_16x16x32_f16(
                    af[tm], bfr[tn], acc[tm][tn], 0, 0, 0);
    }

    __syncthreads();
    // Epilogue: bias add, fp16 convert, re-layout via LDS for coalesced stores.
    _Float16* epi = (_Float16*)lds;  // [128][128]
#pragma unroll
    for (int tm = 0; tm < 4; ++tm) {
#pragma unroll
        for (int tn = 0; tn < 4; ++tn) {
            int col = wn * 64 + tn * 16 + frag;
            float bias = bx[n0 + col];
#pragma unroll
            for (int r = 0; r < 4; ++r) {
                int rowc = wm * 64 + tm * 16 + kg * 4 + r;  // C/D: col=lane&15, row=quad*4+reg
                epi[rowc * 128 + col] = (_Float16)(acc[tm][tn][r] + bias);
            }
        }
    }
    __syncthreads();

    // copy out: each thread -> 64 contiguous fp16 of one row
    int row = tid >> 1;
    int hs = tid & 1;
    int gm = m0 + row;
    int bb = gm >> 11;          // batch
    int tt = gm & 2047;         // time
    int l = n0 / 768;           // 768 % 128 == 0, so a block never crosses l
    int g0 = n0 - l * 768 + hs * 64;
    size_t oidx = (((size_t)bb * 2 + l) * 2048 + tt) * 768 + g0;
    const uint4* s = (const uint4*)(epi + row * 128 + hs * 64);
    uint4* d = (uint4*)(gx + oidx);
#pragma unroll
    for (int j = 0; j < 8; ++j) d[j] = s[j];
}

// ---------------------------------------------------------------------------
// Kernel 2: the recurrence. One block per chain (b, l, dir); 128 blocks.
// 512 threads = 8 waves. Wave w serves units [w*32, w*32+32); within the
// wave, lanes 0-31 (q=0) handle k-cols [0,128), lanes 32-63 (q=1) handle
// [128,256) of the SAME units. Cross-half reduce: one __shfl_xor(32).
// Each thread holds Wh rows {i, 256+i, 512+i}, cols [q*128,q*128+128) as
// 192 packed fp16x2 VGPRs. h fp16 double-buffered in LDS (read as uint4,
// wave-uniform address -> broadcast, conflict-free). gx prefetched one step
// ahead into registers. One barrier per step.
//
// R5: fenced chunked weight-init (peak live <256) + waves_per_eu(2).
// ---------------------------------------------------------------------------
__global__ __launch_bounds__(512)
__attribute__((amdgpu_waves_per_eu(2)))
void gru_scan_kernel(
    const float* __restrict__ Wh,
    const float* __restrict__ bh,
    const _Float16* __restrict__ gx,
    float* __restrict__ out)
{
    const int c = blockIdx.x;
    const int b = c & 31;
    const int l = (c >> 5) & 1;
    const int dir = c >> 6;
    const int tid = threadIdx.x;
    const int wave = tid >> 6;
    const int lane = tid & 63;
    const int q = lane >> 5;               // k-half: 0 -> cols 0-127, 1 -> 128-255
    const int i = wave * 32 + (lane & 31); // output unit 0..255

    __shared__ __align__(16) _Float16 h2[2][256];  // double-buffered fp16 h

    // --- load Wh into registers, fp32 -> fp16x2 (one-time) ---
    // CHUNKED + FENCED: sched_barrier(0) every 2 iterations stops the
    // compiler from hoisting all 192 float2 loads ahead of the converts
    // (which spikes peak pressure >256 and engages the 50/50 AGPR split
    // that cripples the whole kernel). In-flight fp32 <= 12 regs.
    half2_t wr[64], wz[64], wn_[64];
    {
        const float2* pr = (const float2*)(Wh + ((size_t)l * 768 + i) * 256 + q * 128);
        const float2* pz = (const float2*)(Wh + ((size_t)l * 768 + 256 + i) * 256 + q * 128);
        const float2* pn = (const float2*)(Wh + ((size_t)l * 768 + 512 + i) * 256 + q * 128);
#pragma unroll
        for (int j0 = 0; j0 < 64; j0 += 2) {
#pragma unroll
            for (int j = j0; j < j0 + 2; ++j) {
                float2 a = pr[j], bb2 = pz[j], cc = pn[j];
                wr[j]  = (half2_t){(_Float16)a.x, (_Float16)a.y};
                wz[j]  = (half2_t){(_Float16)bb2.x, (_Float16)bb2.y};
                wn_[j] = (half2_t){(_Float16)cc.x, (_Float16)cc.y};
            }
            __builtin_amdgcn_sched_barrier(0);
        }
    }

    // biases AFTER the weight init (keeps init-phase live set minimal)
    const float bhr = bh[l * 768 + i];
    const float bhz = bh[l * 768 + 256 + i];
    const float bhn = bh[l * 768 + 512 + i];

    const _Float16* gxp = gx + (size_t)(b * 2 + l) * 2048 * 768;
    // out flat index: ((b*4096) + t*2 + l)*512 + dir*256 + i
    float* outp = out + (size_t)b * 2048 * 1024 + (size_t)l * 512 + dir * 256 + i;

    if (tid < 256) h2[0][tid] = (_Float16)0.f;

    // preload gx for the first step
    const int t0 = dir ? 2047 : 0;
    float cxr = (float)gxp[(size_t)t0 * 768 + i];
    float cxz = (float)gxp[(size_t)t0 * 768 + 256 + i];
    float cxn = (float)gxp[(size_t)t0 * 768 + 512 + i];
    __syncthreads();

    float hreg = 0.f;

    for (int s = 0; s < 2048; ++s) {
        const int t = dir ? (2047 - s) : s;
        const int sn = (s < 2047) ? (s + 1) : s;
        const int tn = dir ? (2047 - sn) : sn;

        // prefetch next step's gx (hidden behind the dot phase)
        float pxr = (float)gxp[(size_t)tn * 768 + i];
        float pxz = (float)gxp[(size_t)tn * 768 + 256 + i];
        float pxn = (float)gxp[(size_t)tn * 768 + 512 + i];

        // --- dot phase: 3 gates x 64 half2 = 192 v_dot2; h via 16 b128 reads
        //     (wave-uniform LDS address per half-wave -> broadcast) ---
        float ar = 0.f, az = 0.f, an = 0.f;
        const uint4* hbase = (const uint4*)(&h2[s & 1][0]) + (q << 4); // q*256B
#pragma unroll
        for (int j = 0; j < 16; ++j) {
            uint4 hv = hbase[j];
            half2_t h0 = __builtin_bit_cast(half2_t, hv.x);
            half2_t h1 = __builtin_bit_cast(half2_t, hv.y);
            half2_t hg = __builtin_bit_cast(half2_t, hv.z);
            half2_t h3 = __builtin_bit_cast(half2_t, hv.w);
            ar = __builtin_amdgcn_fdot2(wr[4 * j + 0], h0, ar, false);
            az = __builtin_amdgcn_fdot2(wz[4 * j + 0], h0, az, false);
            an = __builtin_amdgcn_fdot2(wn_[4 * j + 0], h0, an, false);
            ar = __builtin_amdgcn_fdot2(wr[4 * j + 1], h1, ar, false);
            az = __builtin_amdgcn_fdot2(wz[4 * j + 1], h1, az, false);
            an = __builtin_amdgcn_fdot2(wn_[4 * j + 1], h1, an, false);
            ar = __builtin_amdgcn_fdot2(wr[4 * j + 2], hg, ar, false);
            az = __builtin_amdgcn_fdot2(wz[4 * j + 2], hg, az, false);
            an = __builtin_amdgcn_fdot2(wn_[4 * j + 2], hg, an, false);
            ar = __builtin_amdgcn_fdot2(wr[4 * j + 3], h3, ar, false);
            az = __builtin_amdgcn_fdot2(wz[4 * j + 3], h3, az, false);
            an = __builtin_amdgcn_fdot2(wn_[4 * j + 3], h3, an, false);
        }

        // cross-half reduction inside the wave (lane i <-> lane i+32)
        ar += __shfl_xor(ar, 32, 64);
        az += __shfl_xor(az, 32, 64);
        an += __shfl_xor(an, 32, 64);

        // --- gate math (all lanes; q=0/q=1 redundantly hold full sums) ---
        float r = sigmoidf_fast(cxr + ar + bhr);
        float z = sigmoidf_fast(cxz + az + bhz);
        float n = tanh_fast(cxn + r * (an + bhn));
        float hnew = (1.f - z) * n + z * hreg;
        hreg = hnew;

        if (q == 0) {
            outp[(size_t)t * 1024] = hnew;
            h2[(s + 1) & 1][i] = (_Float16)hnew;
        }
        cxr = pxr; cxz = pxz; cxn = pxn;
        __syncthreads();
    }
}

// ---------------------------------------------------------------------------
extern "C" void kernel_launch(void* const* d_in, const int* in_sizes, int n_in,
                              void* d_out, int out_size, void* d_ws, size_t ws_size,
                              hipStream_t stream) {
    const float* x  = (const float*)d_in[0];  // (32,2048,256) fp32
    const float* Wx = (const float*)d_in[1];  // (2,768,256)  fp32
    const float* Wh = (const float*)d_in[2];  // (2,768,256)  fp32
    const float* bx = (const float*)d_in[3];  // (2,768)      fp32
    const float* bh = (const float*)d_in[4];  // (2,768)      fp32
    float* out = (float*)d_out;               // (32,4096,512) fp32
    _Float16* gxbuf = (_Float16*)d_ws;        // 100,663,296 fp16 = 201.3 MB

    // Phase 1: gx = x @ Wx^T + bx  (layout [b][l][t][768], fp16)
    gemm_gx_kernel<<<dim3(512, 12), 256, 0, stream>>>(x, Wx, bx, gxbuf);

    // Phase 2: 128 independent (b, l, dir) GRU chains
    gru_scan_kernel<<<dim3(128), 512, 0, stream>>>(Wh, bh, gxbuf, out);
}